// Round 1
// 443.794 us; speedup vs baseline: 1.0296x; 1.0296x over previous
//
#include <hip/hip_runtime.h>

// Conv x(32,64,128,128) * w(128,64,3,3) VALID + ReLU -> (32,128,126,126) flat.
// Per-tap implicit GEMM, bf16 MFMA 16x16x32, fp32 acc.
// Tile: 128 kout x 128 sp (one full output row) per block, 4 waves.
// This version: double-buffered Bs + async stage split (issue next row's global
// loads BEFORE the 3-tap compute, pack+write AFTER) -> stage latency hides under
// MFMA; one barrier per r instead of two. Tail staging (rows 128..131) removed:
// those rows only feed sp>=126 outputs, which are masked at the store, and MFMA
// NaN/garbage containment is per-output-column.

#define OUT0_SIZE (32 * 128 * 15876)
#define X_TOTAL   (32 * 64 * 128 * 128)

typedef __attribute__((ext_vector_type(8))) short short8v;   // 8 bf16 (4 VGPRs)
typedef __attribute__((ext_vector_type(4))) float float4v;   // MFMA C/D

static __device__ __forceinline__ unsigned bf16_rn(float f) {
  unsigned u = __float_as_uint(f);
  u += 0x7FFFu + ((u >> 16) & 1u);   // RNE; inputs are finite normals
  return u >> 16;
}
static __device__ __forceinline__ unsigned pk2(float a, float b) {
  return bf16_rn(a) | (bf16_rn(b) << 16);
}

// Prepass: w[kout][c][r][s] fp32 -> wt[tap=r*3+s][kout][c] bf16 (147 KB, L2-resident)
__global__ void repack_w(const float* __restrict__ w, unsigned short* __restrict__ wt) {
  int o = blockIdx.x * 256 + threadIdx.x;       // 9*128*64 = 73728
  if (o >= 9 * 128 * 64) return;
  int tap  = o >> 13;
  int rem  = o & 8191;
  int kout = rem >> 6;
  int c    = rem & 63;
  wt[o] = (unsigned short)bf16_rn(w[kout * 576 + c * 9 + tap]);
}

__global__ __launch_bounds__(256, 2) void conv3x3_relu_mfma(
    const float* __restrict__ x, const unsigned short* __restrict__ wt,
    float* __restrict__ out) {
  // Bs[buf][row=sp 0..131][64 c], 128 B rows, chunk-of-16B swizzle pos = ch ^ ((row>>1)&7).
  // Rows 128..131 are never written (reads of 128/129 feed only masked outputs).
  __shared__ __align__(16) unsigned short Bs[2][132 * 64];   // 33 KB

  const int tid  = threadIdx.x;
  const int wv   = tid >> 6;
  const int lane = tid & 63;
  const int l15  = lane & 15;
  const int quad = lane >> 4;

  // XCD-aware oh swizzle: strip of 16 consecutive oh per (blockIdx.x % 8) so the
  // 3x cross-oh x-row reuse stays inside one XCD's L2.
  const int bx = blockIdx.x;                 // 0..127
  const int oh = (bx & 7) * 16 + (bx >> 3);
  if (oh >= 126) return;                     // 2 dead bx values
  const int n = blockIdx.y;

  float4v acc[2][8];
#pragma unroll
  for (int i = 0; i < 2; ++i)
#pragma unroll
    for (int j = 0; j < 8; ++j)
      acc[i][j] = (float4v){0.f, 0.f, 0.f, 0.f};

  // staging mapping: lane -> sp-pair (coalesced float2), wave -> c-octet
  const int spp = tid & 63;
  const int c8a = tid >> 6;                  // 0..3 (+4 on second half)
  const int xbase = n * 1048576 + oh * 128;

  // A-frag pipeline: load tap 0 before anything else
  short8v a_cur[2][2], a_nxt[2][2];
#pragma unroll
  for (int i = 0; i < 2; ++i)
#pragma unroll
    for (int kk = 0; kk < 2; ++kk)
      a_cur[i][kk] = *(const short8v*)(wt + (wv * 32 + i * 16 + l15) * 64 + kk * 32 + quad * 8);

  float2 v[2][8];                            // in-flight staging registers

  // ---- prologue: stage r=0 into Bs[0] ----
  {
    const float* xp = x + xbase + 2 * spp;
#pragma unroll
    for (int half = 0; half < 2; ++half)
#pragma unroll
      for (int j = 0; j < 8; ++j)
        v[half][j] = *(const float2*)(xp + ((c8a + half * 4) * 8 + j) * 16384);
#pragma unroll
    for (int half = 0; half < 2; ++half) {
      const int c8  = c8a + half * 4;
      const int pos = c8 ^ (spp & 7);
      uint4 lo = make_uint4(pk2(v[half][0].x, v[half][1].x), pk2(v[half][2].x, v[half][3].x),
                            pk2(v[half][4].x, v[half][5].x), pk2(v[half][6].x, v[half][7].x));
      uint4 hi = make_uint4(pk2(v[half][0].y, v[half][1].y), pk2(v[half][2].y, v[half][3].y),
                            pk2(v[half][4].y, v[half][5].y), pk2(v[half][6].y, v[half][7].y));
      *(uint4*)&Bs[0][(2 * spp)     * 64 + pos * 8] = lo;
      *(uint4*)&Bs[0][(2 * spp + 1) * 64 + pos * 8] = hi;
    }
  }
  __syncthreads();

  for (int r = 0; r < 3; ++r) {
    // ---- issue next raw row's global loads; consumed AFTER the compute below ----
    if (r < 2) {
      const float* xp = x + xbase + (r + 1) * 128 + 2 * spp;
#pragma unroll
      for (int half = 0; half < 2; ++half)
#pragma unroll
        for (int j = 0; j < 8; ++j)
          v[half][j] = *(const float2*)(xp + ((c8a + half * 4) * 8 + j) * 16384);
    }

    // ---- 3 taps off buffer r&1; A for next tap prefetched during compute ----
    const unsigned short* Bp = &Bs[r & 1][0];
#pragma unroll
    for (int s = 0; s < 3; ++s) {
      const int ntap = r * 3 + s + 1;        // next tap to prefetch
      if (ntap < 9) {
#pragma unroll
        for (int i = 0; i < 2; ++i)
#pragma unroll
          for (int kk = 0; kk < 2; ++kk)
            a_nxt[i][kk] = *(const short8v*)(wt + ntap * 8192 +
                (wv * 32 + i * 16 + l15) * 64 + kk * 32 + quad * 8);
      }
#pragma unroll
      for (int j = 0; j < 8; ++j) {
        const int row = j * 16 + l15 + s;
        const int sw  = (row >> 1) & 7;
#pragma unroll
        for (int kk = 0; kk < 2; ++kk) {
          const int pos = (kk * 4 + quad) ^ sw;
          short8v b = *(const short8v*)&Bp[row * 64 + pos * 8];
          acc[0][j] = __builtin_amdgcn_mfma_f32_16x16x32_bf16(a_cur[0][kk], b, acc[0][j], 0, 0, 0);
          acc[1][j] = __builtin_amdgcn_mfma_f32_16x16x32_bf16(a_cur[1][kk], b, acc[1][j], 0, 0, 0);
        }
      }
#pragma unroll
      for (int i = 0; i < 2; ++i)
#pragma unroll
        for (int kk = 0; kk < 2; ++kk)
          a_cur[i][kk] = a_nxt[i][kk];
    }

    // ---- pack + write next buffer (loads have been in flight under compute) ----
    if (r < 2) {
      const int nb = (r + 1) & 1;
#pragma unroll
      for (int half = 0; half < 2; ++half) {
        const int c8  = c8a + half * 4;
        const int pos = c8 ^ (spp & 7);
        uint4 lo = make_uint4(pk2(v[half][0].x, v[half][1].x), pk2(v[half][2].x, v[half][3].x),
                              pk2(v[half][4].x, v[half][5].x), pk2(v[half][6].x, v[half][7].x));
        uint4 hi = make_uint4(pk2(v[half][0].y, v[half][1].y), pk2(v[half][2].y, v[half][3].y),
                              pk2(v[half][4].y, v[half][5].y), pk2(v[half][6].y, v[half][7].y));
        *(uint4*)&Bs[nb][(2 * spp)     * 64 + pos * 8] = lo;
        *(uint4*)&Bs[nb][(2 * spp + 1) * 64 + pos * 8] = hi;
      }
      __syncthreads();   // one barrier per r: next-buffer writes visible
    }
  }

  // ---- epilogue: ReLU + store. C/D: col=l15 (sp), row=quad*4+reg (kout) ----
  const int ob = n * 128 * 15876 + oh * 126;
#pragma unroll
  for (int i = 0; i < 2; ++i)
#pragma unroll
    for (int j = 0; j < 8; ++j) {
      const int sp = j * 16 + l15;
      if (sp < 126) {
#pragma unroll
        for (int reg = 0; reg < 4; ++reg) {
          const int kout = wv * 32 + i * 16 + quad * 4 + reg;
          out[ob + kout * 15876 + sp] = fmaxf(acc[i][j][reg], 0.0f);
        }
      }
    }
}

// Output 1: concat(a,b) last dim -> (1024, 2048), float4 copy.
__global__ void concat_kernel(const float* __restrict__ a,
                              const float* __restrict__ b,
                              float* __restrict__ o) {
  int i   = blockIdx.x * 256 + threadIdx.x;  // 524288 float4
  int row = i >> 9;
  int col = i & 511;
  const float4* src = (col < 256) ? (const float4*)a + (row << 8) + col
                                  : (const float4*)b + (row << 8) + (col - 256);
  ((float4*)o)[i] = *src;
}

extern "C" void kernel_launch(void* const* d_in, const int* in_sizes, int n_in,
                              void* d_out, int out_size, void* d_ws, size_t ws_size,
                              hipStream_t stream) {
  const float* x = (const float*)d_in[0];
  const float* w = (const float*)d_in[1];
  const float* a = (const float*)d_in[2];
  const float* b = (const float*)d_in[3];

  float* out0 = (float*)d_out;
  float* out1 = out0 + OUT0_SIZE;
  unsigned short* wt = (unsigned short*)d_ws;   // 147456 B

  repack_w<<<288, 256, 0, stream>>>(w, wt);
  dim3 grid(128, 32);
  conv3x3_relu_mfma<<<grid, 256, 0, stream>>>(x, wt, out0);
  concat_kernel<<<2048, 256, 0, stream>>>(a, b, out1);
}